// Round 4
// baseline (789.973 us; speedup 1.0000x reference)
//
#include <hip/hip_runtime.h>
#include <cstdint>
#include <cstddef>

using u16 = unsigned short;
using f32x4 = __attribute__((ext_vector_type(4))) float;
using bf8   = __attribute__((ext_vector_type(8))) short;   // 8 bf16 in 4 VGPRs

#define DEVFN __device__ __forceinline__

constexpr int BB  = 2;
constexpr int LQ  = 2048;
constexpr int LKV = 4096;
constexpr int DD  = 2048;
constexpr int NH  = 16;
constexpr int HDm = 128;
constexpr float ATTN_SCALE = 0.08838834764831845f;  // 128^-0.5
constexpr float LN_EPS = 1e-6f;
// softmax fixed shift: LN guarantees |s| <= ||q*scale||*||k|| = 1*sqrt(128) ~ 11.4
constexpr float LOG2E  = 1.4426950408889634f;
constexpr float SHIFT2 = 17.312340490667562f;       // 12.0 * log2(e)

DEVFN u16 f2bf(float f) {
  unsigned u = __builtin_bit_cast(unsigned, f);
  u += 0x7fffu + ((u >> 16) & 1u);          // RNE
  return (u16)(u >> 16);
}
DEVFN float bf2f(u16 h) { return __builtin_bit_cast(float, (unsigned)h << 16); }
DEVFN f32x4 mfma16(bf8 a, bf8 b, f32x4 c) {
  return __builtin_amdgcn_mfma_f32_16x16x32_bf16(a, b, c, 0, 0, 0);
}
// async global->LDS, 16B/lane, lane i lands at lds + i*16 (wave-uniform lds base)
DEVFN void gl16(const void* g, void* l) {
  __builtin_amdgcn_global_load_lds(
      (const __attribute__((address_space(1))) void*)g,
      (__attribute__((address_space(3))) void*)l, 16, 0, 0);
}
DEVFN void barrier_hard() {                 // raw barrier + scheduler fence
  __builtin_amdgcn_s_barrier();
  __builtin_amdgcn_sched_barrier(0);
}

// ---------------- f32 -> bf16 convert (4 el/thread) ----------------
__global__ __launch_bounds__(256) void k_cvt(const float4* __restrict__ in,
                                             ushort4* __restrict__ out, int n4) {
  int i = blockIdx.x * 256 + threadIdx.x;
  if (i >= n4) return;
  float4 v = in[i];
  ushort4 o;
  o.x = f2bf(v.x); o.y = f2bf(v.y); o.z = f2bf(v.z); o.w = f2bf(v.w);
  out[i] = o;
}

// ---------------- bf16 NT GEMM: Y[M,N] = X[M,K] * W[N,K]^T + bias[N] -------
// 128x128 tile, BK=64, 4 waves, gl16 staging + XOR swizzle.
// MODE: 1 = f32 out (nontemporal); 2 = bf16 + per-head LN;
//       3 = bf16 + per-head LN + ATTN_SCALE;
//       4 = bf16 TRANSPOSED per-head out -> Y[bh][hd][kv]  (fused V-transpose)
template <int MODE>
__global__ __launch_bounds__(256) void k_gemm_nt(const u16* __restrict__ X,
                                                 const u16* __restrict__ Wt,
                                                 const float* __restrict__ bias,
                                                 const float* __restrict__ lng,
                                                 const float* __restrict__ lnb,
                                                 void* __restrict__ Y,
                                                 int M, int N, int K) {
  __shared__ __align__(16) u16 Sh[2][128 * 64];   // As | Bs ; reused as T[128][128]
  __shared__ float Sm[2][128], Sq[2][128];
  u16* As = Sh[0];
  u16* Bs = Sh[1];
  const int tid = threadIdx.x;
  const int w = tid >> 6, l = tid & 63;
  const int m0 = blockIdx.x * 128, n0 = blockIdx.y * 128;
  const int wr = w >> 1, wc = w & 1;
  const int lr = l & 15, lk = (l >> 4) * 8;
  const int rsw = (l & 7) << 3;               // read-side swizzle (u16 units)
  const int srow = l >> 3;
  const int scb = (l & 7) * 16;
  f32x4 acc[4][4] = {};

  for (int k0 = 0; k0 < K; k0 += 64) {
#pragma unroll
    for (int i = 0; i < 4; ++i) {
      int rbase = w * 32 + i * 8;
      int row = rbase + srow;
      int cb = scb ^ ((row & 7) << 4);        // inverse-swizzled source col (bytes)
      gl16((const char*)&X[(size_t)(m0 + row) * K + k0] + cb, &As[rbase * 64]);
      gl16((const char*)&Wt[(size_t)(n0 + row) * K + k0] + cb, &Bs[rbase * 64]);
    }
    __syncthreads();
    bf8 af[4][2], bfr[4][2];
#pragma unroll
    for (int mi = 0; mi < 4; ++mi)
#pragma unroll
      for (int kk = 0; kk < 2; ++kk)
        af[mi][kk] = *(const bf8*)&As[(wr * 64 + mi * 16 + lr) * 64 + ((kk * 32 + lk) ^ rsw)];
#pragma unroll
    for (int ni = 0; ni < 4; ++ni)
#pragma unroll
      for (int kk = 0; kk < 2; ++kk)
        bfr[ni][kk] = *(const bf8*)&Bs[(wc * 64 + ni * 16 + lr) * 64 + ((kk * 32 + lk) ^ rsw)];
#pragma unroll
    for (int kk = 0; kk < 2; ++kk)
#pragma unroll
      for (int mi = 0; mi < 4; ++mi)
#pragma unroll
        for (int ni = 0; ni < 4; ++ni)
          acc[mi][ni] = mfma16(af[mi][kk], bfr[ni][kk], acc[mi][ni]);
    __syncthreads();
  }
  const int lrg = (l >> 4) * 4;

  // bias (pre-LN, matching reference: LN(x@W^T + b))
  float bv[4];
#pragma unroll
  for (int ni = 0; ni < 4; ++ni) bv[ni] = bias[n0 + wc * 64 + ni * 16 + lr];
#pragma unroll
  for (int mi = 0; mi < 4; ++mi)
#pragma unroll
    for (int ni = 0; ni < 4; ++ni)
#pragma unroll
      for (int r = 0; r < 4; ++r) acc[mi][ni][r] += bv[ni];

  if constexpr (MODE == 2 || MODE == 3) {
    // per-row partial sums over this wave's 64 cols -> LDS -> combine
#pragma unroll
    for (int mi = 0; mi < 4; ++mi) {
#pragma unroll
      for (int r = 0; r < 4; ++r) {
        float ps = 0.f, pq = 0.f;
#pragma unroll
        for (int ni = 0; ni < 4; ++ni) {
          float v = acc[mi][ni][r];
          ps += v; pq += v * v;
        }
#pragma unroll
        for (int m = 1; m < 16; m <<= 1) {
          ps += __shfl_xor(ps, m);
          pq += __shfl_xor(pq, m);
        }
        if (lr == 0) {
          int rl = wr * 64 + mi * 16 + lrg + r;
          Sm[wc][rl] = ps; Sq[wc][rl] = pq;
        }
      }
    }
    __syncthreads();
    float gv[4], bbv[4];
#pragma unroll
    for (int ni = 0; ni < 4; ++ni) {
      int c = wc * 64 + ni * 16 + lr;          // col within head (n-tile aligned)
      gv[ni] = lng[c]; bbv[ni] = lnb[c];
    }
#pragma unroll
    for (int mi = 0; mi < 4; ++mi)
#pragma unroll
      for (int r = 0; r < 4; ++r) {
        int rl = wr * 64 + mi * 16 + lrg + r;
        float mean = (Sm[0][rl] + Sm[1][rl]) * (1.f / 128.f);
        float var  = (Sq[0][rl] + Sq[1][rl]) * (1.f / 128.f) - mean * mean;
        float rs = rsqrtf(var + LN_EPS);
#pragma unroll
        for (int ni = 0; ni < 4; ++ni) {
          float o = (acc[mi][ni][r] - mean) * rs * gv[ni] + bbv[ni];
          if (MODE == 3) o *= ATTN_SCALE;
          acc[mi][ni][r] = o;
        }
      }
  }

  if constexpr (MODE == 4) {
    // fused V-transpose: stage 128x128 bf16 tile in LDS (swizzled cols),
    // then write Y[bh][hd][kv] coalesced along kv.
    u16* T = &Sh[0][0];                        // 128*128 u16 = 32 KB
#pragma unroll
    for (int mi = 0; mi < 4; ++mi)
#pragma unroll
      for (int ni = 0; ni < 4; ++ni)
#pragma unroll
        for (int r = 0; r < 4; ++r) {
          int mrow = wr * 64 + mi * 16 + lrg + r;
          int ncol = wc * 64 + ni * 16 + lr;
          T[mrow * 128 + (ncol ^ ((mrow & 7) << 3))] = f2bf(acc[mi][ni][r]);
        }
    __syncthreads();
    int hd = tid >> 1, half = tid & 1;
    int bq = m0 >> 12;                          // m = b*LKV + kv, LKV=4096
    int kvb = (m0 & (LKV - 1)) + half * 64;
    int hh = n0 >> 7;                           // n-tile == head
    u16* vout = (u16*)Y + ((size_t)(bq * NH + hh) * HDm + hd) * LKV + kvb;
#pragma unroll
    for (int j8 = 0; j8 < 8; ++j8) {
      u16 tmp[8] __attribute__((aligned(16)));
#pragma unroll
      for (int j = 0; j < 8; ++j) {
        int kv = half * 64 + j8 * 8 + j;
        tmp[j] = T[kv * 128 + (hd ^ ((kv & 7) << 3))];
      }
      *(int4*)&vout[j8 * 8] = *(const int4*)tmp;
    }
    return;
  }

#pragma unroll
  for (int ni = 0; ni < 4; ++ni) {
    int n = n0 + wc * 64 + ni * 16 + lr;
#pragma unroll
    for (int mi = 0; mi < 4; ++mi) {
      int mb = m0 + wr * 64 + mi * 16 + lrg;
#pragma unroll
      for (int r = 0; r < 4; ++r) {
        float v = acc[mi][ni][r];
        if constexpr (MODE == 1)
          __builtin_nontemporal_store(v, &((float*)Y)[(size_t)(mb + r) * N + n]);
        else
          ((u16*)Y)[(size_t)(mb + r) * N + n] = f2bf(v);
      }
    }
  }
}

// ---------------- fused attention ------------------------------------------
// 512 threads / 8 waves, q-tile 128, kv-tile 64. LDS: Ks dbuf 32K + Vs dbuf
// 32K + Ps 16K = 80K -> 2 blocks/CU. Counted vmcnt: Wout stores never drained
// in-loop. T15 pipeline: softmax+PV of tile t-1 overlap QK of tile t.
__global__ __launch_bounds__(512, 4) void k_attn(const u16* __restrict__ Qp,
                                                 const u16* __restrict__ Kp,
                                                 const u16* __restrict__ Vt,
                                                 float* __restrict__ Wout,
                                                 u16* __restrict__ AO) {
  const int g = blockIdx.x;                 // 512 blocks, 8 XCDs, 64 each
  const int work = (g & 7) * 64 + (g >> 3);
  const int bh = work >> 4;
  const int b = bh >> 4, h = bh & 15;
  const int q0 = (work & 15) * 128;
  const int tid = threadIdx.x, w = tid >> 6, l = tid & 63;
  const int lr = l & 15, lk = (l >> 4) * 8, lrg = (l >> 4) * 4;
  const int rsw = (l & 7) << 3;             // read swizzle, u16 units
  __shared__ __align__(16) u16 Ks[2][64 * 128];
  __shared__ __align__(16) u16 Vs[2][128 * 64];
  __shared__ __align__(16) u16 Ps[8][16 * 64];

  // hoist Q fragments (A-frag: row = lr, k = lk + kc*32)
  bf8 qf[4];
  {
    const u16* qb = &Qp[((size_t)b * LQ + q0 + w * 16 + lr) * DD + h * HDm];
#pragma unroll
    for (int kc = 0; kc < 4; ++kc) qf[kc] = *(const bf8*)(qb + kc * 32 + lk);
  }
  const u16* Kb = Kp + (size_t)b * LKV * DD + h * HDm;   // row stride DD
  const u16* Vb = Vt + (size_t)bh * HDm * LKV;           // row (hd) stride LKV

  auto stageK = [&](int buf, int kv0) {
#pragma unroll
    for (int i = 0; i < 2; ++i) {
      int rbase = i * 32 + w * 4;           // wave-uniform
      int row = rbase + (l >> 4);
      int cb = ((l & 15) * 16) ^ ((row & 7) << 4);
      gl16((const char*)(Kb + (size_t)(kv0 + row) * DD) + cb, &Ks[buf][rbase * 128]);
    }
  };
  auto stageV = [&](int buf, int kv0) {
#pragma unroll
    for (int i = 0; i < 2; ++i) {
      int rbase = i * 64 + w * 8;
      int row = rbase + (l >> 3);
      int cb = ((l & 7) * 16) ^ ((row & 7) << 4);
      gl16((const char*)(Vb + (size_t)row * LKV + kv0) + cb, &Vs[buf][rbase * 64]);
    }
  };
  auto qk_tile = [&](int t, f32x4 (&s)[4]) {
    const u16* ks = Ks[t & 1];
    __builtin_amdgcn_s_setprio(1);
#pragma unroll
    for (int ni = 0; ni < 4; ++ni) {
      s[ni] = f32x4{0.f, 0.f, 0.f, 0.f};
#pragma unroll
      for (int kc = 0; kc < 4; ++kc) {
        bf8 kf = *(const bf8*)&ks[(ni * 16 + lr) * 128 + ((kc * 32 + lk) ^ rsw)];
        s[ni] = mfma16(qf[kc], kf, s[ni]);
      }
    }
    __builtin_amdgcn_s_setprio(0);
  };

  // ================= pass A: row sums of exp2(s*log2e - SHIFT2) ============
  float lsum[4] = {0.f, 0.f, 0.f, 0.f};
  auto sumexp = [&](const f32x4 (&s)[4]) {
#pragma unroll
    for (int ni = 0; ni < 4; ++ni)
#pragma unroll
      for (int r = 0; r < 4; ++r)
        lsum[r] += exp2f(fmaf(s[ni][r], LOG2E, -SHIFT2));
  };
  f32x4 sA[4], sB[4];
  stageK(0, 0);
  asm volatile("s_waitcnt vmcnt(0)" ::: "memory");
  barrier_hard();
  stageK(1, 64);
  qk_tile(0, sA);
  asm volatile("s_waitcnt vmcnt(0)" ::: "memory");
  barrier_hard();
  for (int t = 1; t < 64; t += 2) {
    if (t < 63) stageK((t + 1) & 1, (t + 1) * 64);
    qk_tile(t, sB);
    sumexp(sA);                              // VALU overlaps QK MFMA
    asm volatile("s_waitcnt vmcnt(0)" ::: "memory");
    barrier_hard();
    if (t + 1 < 64) {
      if (t + 1 < 63) stageK((t + 2) & 1, (t + 2) * 64);
      qk_tile(t + 1, sA);
      sumexp(sB);
      asm volatile("s_waitcnt vmcnt(0)" ::: "memory");
      barrier_hard();
    }
  }
  sumexp(sB);                                // tile 63
  // per-row: reduce over 16 lanes; fold 1/sum into exponent offset c[r]
  float cr[4];
#pragma unroll
  for (int r = 0; r < 4; ++r) {
    float v = lsum[r];
#pragma unroll
    for (int m = 1; m < 16; m <<= 1) v += __shfl_xor(v, m);
    cr[r] = -(SHIFT2 + __log2f(v));
  }

  // ================= pass B: weights + PV (T15 pipelined) ==================
  f32x4 oacc[8] = {};
  float* wbase = Wout + ((size_t)bh * LQ + q0 + w * 16 + lrg) * LKV;
  auto finish = [&](int tp, const f32x4 (&s)[4]) {   // softmax+Wout+Ps+PV of tile tp
    const int kv0 = tp * 64;
#pragma unroll
    for (int ni = 0; ni < 4; ++ni) {
#pragma unroll
      for (int r = 0; r < 4; ++r) {
        float p = exp2f(fmaf(s[ni][r], LOG2E, cr[r]));
        __builtin_nontemporal_store(p, &wbase[(size_t)r * LKV + kv0 + ni * 16 + lr]);
        int row = lrg + r;
        Ps[w][row * 64 + ((ni * 16 + lr) ^ ((row & 7) << 3))] = f2bf(p);
      }
    }
    asm volatile("s_waitcnt lgkmcnt(0)" ::: "memory");   // Ps per-wave
    __builtin_amdgcn_sched_barrier(0);
    __builtin_amdgcn_s_setprio(1);
#pragma unroll
    for (int kk = 0; kk < 2; ++kk) {
      bf8 pf = *(const bf8*)&Ps[w][lr * 64 + ((kk * 32 + lk) ^ rsw)];
#pragma unroll
      for (int c = 0; c < 8; ++c) {
        bf8 vf = *(const bf8*)&Vs[tp & 1][(c * 16 + lr) * 64 + ((kk * 32 + lk) ^ rsw)];
        oacc[c] = mfma16(pf, vf, oacc[c]);
      }
    }
    __builtin_amdgcn_s_setprio(0);
  };

  stageK(0, 0);
  asm volatile("s_waitcnt vmcnt(0)" ::: "memory");
  barrier_hard();
  stageK(1, 64); stageV(0, 0);
  qk_tile(0, sA);
  asm volatile("s_waitcnt vmcnt(0)" ::: "memory");
  barrier_hard();
  for (int t = 1; t < 64; t += 2) {
    // iter t: compute tile t, finish tile t-1
    if (t < 63) stageK((t + 1) & 1, (t + 1) * 64);
    stageV(t & 1, t * 64);
    qk_tile(t, sB);
    finish(t - 1, sA);
    asm volatile("s_waitcnt vmcnt(16)" ::: "memory");  // drain loads, keep stores
    barrier_hard();
    if (t + 1 < 64) {
      if (t + 1 < 63) stageK((t + 2) & 1, (t + 2) * 64);
      stageV((t + 1) & 1, (t + 1) * 64);
      qk_tile(t + 1, sA);
      finish(t, sB);
      asm volatile("s_waitcnt vmcnt(16)" ::: "memory");
      barrier_hard();
    }
  }
  finish(63, sB);                            // tail: tile 63 (Vs[1] staged @t=63)

  // epilogue: AO [B, Lq, D] bf16 (re-read by O-proj -> normal stores)
#pragma unroll
  for (int c = 0; c < 8; ++c)
#pragma unroll
    for (int r = 0; r < 4; ++r)
      AO[((size_t)b * LQ + q0 + w * 16 + lrg + r) * DD + h * HDm + c * 16 + lr] =
          f2bf(oacc[c][r]);
}

// ---------------------------------------------------------------------------
extern "C" void kernel_launch(void* const* d_in, const int* in_sizes, int n_in,
                              void* d_out, int out_size, void* d_ws, size_t ws_size,
                              hipStream_t stream) {
  const float* hs   = (const float*)d_in[0];
  const float* cas  = (const float*)d_in[1];
  const float* q_w  = (const float*)d_in[2];
  const float* q_b  = (const float*)d_in[3];
  const float* k_w  = (const float*)d_in[4];
  const float* k_b  = (const float*)d_in[5];
  const float* v_w  = (const float*)d_in[6];
  const float* v_b  = (const float*)d_in[7];
  const float* o_w  = (const float*)d_in[8];
  const float* o_b  = (const float*)d_in[9];
  const float* qn_g = (const float*)d_in[10];
  const float* qn_b = (const float*)d_in[11];
  const float* kn_g = (const float*)d_in[12];
  const float* kn_b = (const float*)d_in[13];

  float* out_attn = (float*)d_out;
  float* out_w    = out_attn + (size_t)BB * LQ * DD;

  constexpr size_t SZ_Q  = (size_t)BB * LQ * DD * 2;
  constexpr size_t SZ_KV = (size_t)BB * LKV * DD * 2;
  constexpr size_t SZ_W  = (size_t)DD * DD * 2;
  char* p = (char*)d_ws;
  u16* hsb  = (u16*)p;              p += SZ_Q;
  u16* casb = (u16*)p;              p += SZ_KV;
  u16* qwb  = (u16*)p;              p += SZ_W;
  u16* kwb  = (u16*)p;              p += SZ_W;
  u16* vwb  = (u16*)p;              p += SZ_W;
  u16* owb  = (u16*)p;              p += SZ_W;
  u16* Qp   = (u16*)p;              p += SZ_Q;
  u16* Kp   = (u16*)p;              p += SZ_KV;
  u16* Vtp  = (u16*)p;              p += SZ_KV;
  u16* AO   = (u16*)p;              p += SZ_Q;

  auto cvt = [&](const float* src, u16* dst, size_t n) {
    int n4 = (int)(n / 4);
    k_cvt<<<dim3((n4 + 255) / 256), dim3(256), 0, stream>>>(
        (const float4*)src, (ushort4*)dst, n4);
  };
  cvt(hs,  hsb,  (size_t)BB * LQ * DD);
  cvt(cas, casb, (size_t)BB * LKV * DD);
  cvt(q_w, qwb, (size_t)DD * DD);
  cvt(k_w, kwb, (size_t)DD * DD);
  cvt(v_w, vwb, (size_t)DD * DD);
  cvt(o_w, owb, (size_t)DD * DD);

  // projections; LN fused for Q (with ATTN_SCALE) and K; V writes transposed
  k_gemm_nt<3><<<dim3(BB * LQ / 128, DD / 128), dim3(256), 0, stream>>>(
      hsb, qwb, q_b, qn_g, qn_b, Qp, BB * LQ, DD, DD);
  k_gemm_nt<2><<<dim3(BB * LKV / 128, DD / 128), dim3(256), 0, stream>>>(
      casb, kwb, k_b, kn_g, kn_b, Kp, BB * LKV, DD, DD);
  k_gemm_nt<4><<<dim3(BB * LKV / 128, DD / 128), dim3(256), 0, stream>>>(
      casb, vwb, v_b, nullptr, nullptr, Vtp, BB * LKV, DD, DD);

  k_attn<<<dim3(LQ / 128 * BB * NH), dim3(512), 0, stream>>>(Qp, Kp, Vtp, out_w, AO);

  k_gemm_nt<1><<<dim3(BB * LQ / 128, DD / 128), dim3(256), 0, stream>>>(
      AO, owb, o_b, nullptr, nullptr, out_attn, BB * LQ, DD, DD);
}

// Round 6
// 753.493 us; speedup vs baseline: 1.0484x; 1.0484x over previous
//
#include <hip/hip_runtime.h>
#include <cstdint>
#include <cstddef>

using u16 = unsigned short;
using f32x4 = __attribute__((ext_vector_type(4))) float;
using bf8   = __attribute__((ext_vector_type(8))) short;   // 8 bf16 in 4 VGPRs
using u32x4 = __attribute__((ext_vector_type(4))) unsigned;

#define DEVFN __device__ __forceinline__

constexpr int BB  = 2;
constexpr int LQ  = 2048;
constexpr int LKV = 4096;
constexpr int DD  = 2048;
constexpr int NH  = 16;
constexpr int HDm = 128;
constexpr float ATTN_SCALE = 0.08838834764831845f;  // 128^-0.5
constexpr float LN_EPS = 1e-6f;
// softmax fixed shift: LN guarantees |s| <= ||q*scale||*||k|| = 1*sqrt(128) ~ 11.4
constexpr float LOG2E  = 1.4426950408889634f;
constexpr float SHIFT2 = 17.312340490667562f;       // 12.0 * log2(e)

DEVFN u16 f2bf(float f) {
  unsigned u = __builtin_bit_cast(unsigned, f);
  u += 0x7fffu + ((u >> 16) & 1u);          // RNE
  return (u16)(u >> 16);
}
DEVFN float bf2f(u16 h) { return __builtin_bit_cast(float, (unsigned)h << 16); }
DEVFN f32x4 mfma16(bf8 a, bf8 b, f32x4 c) {
  return __builtin_amdgcn_mfma_f32_16x16x32_bf16(a, b, c, 0, 0, 0);
}
// async global->LDS, 16B/lane, lane i lands at lds + i*16 (wave-uniform lds base)
DEVFN void gl16(const void* g, void* l) {
  __builtin_amdgcn_global_load_lds(
      (const __attribute__((address_space(1))) void*)g,
      (__attribute__((address_space(3))) void*)l, 16, 0, 0);
}
DEVFN void barrier_hard() {                 // raw barrier + scheduler fence
  __builtin_amdgcn_s_barrier();
  __builtin_amdgcn_sched_barrier(0);
}

// ---------------- f32 -> bf16 convert (4 el/thread) ----------------
__global__ __launch_bounds__(256) void k_cvt(const float4* __restrict__ in,
                                             ushort4* __restrict__ out, int n4) {
  int i = blockIdx.x * 256 + threadIdx.x;
  if (i >= n4) return;
  float4 v = in[i];
  ushort4 o;
  o.x = f2bf(v.x); o.y = f2bf(v.y); o.z = f2bf(v.z); o.w = f2bf(v.w);
  out[i] = o;
}

// ---------------- bf16 NT GEMM: Y[M,N] = X[M,K] * W[N,K]^T + bias[N] -------
// 128x128 tile, BK=64, 4 waves, gl16 staging + XOR swizzle.
// MODE: 1 = f32 out (nontemporal); 2 = bf16 + per-head LN;
//       3 = bf16 + per-head LN + ATTN_SCALE;
//       4 = bf16 TRANSPOSED per-head out -> Y[bh][hd][kv]  (fused V-transpose)
template <int MODE>
__global__ __launch_bounds__(256) void k_gemm_nt(const u16* __restrict__ X,
                                                 const u16* __restrict__ Wt,
                                                 const float* __restrict__ bias,
                                                 const float* __restrict__ lng,
                                                 const float* __restrict__ lnb,
                                                 void* __restrict__ Y,
                                                 int M, int N, int K) {
  __shared__ __align__(16) u16 Sh[2][128 * 64];   // As | Bs ; reused as T[128][128]
  __shared__ float Sm[2][128], Sq[2][128];
  u16* As = Sh[0];
  u16* Bs = Sh[1];
  const int tid = threadIdx.x;
  const int w = tid >> 6, l = tid & 63;
  const int m0 = blockIdx.x * 128, n0 = blockIdx.y * 128;
  const int wr = w >> 1, wc = w & 1;
  const int lr = l & 15, lk = (l >> 4) * 8;
  const int rsw = (l & 7) << 3;               // read-side swizzle (u16 units)
  const int srow = l >> 3;
  const int scb = (l & 7) * 16;
  f32x4 acc[4][4] = {};

  for (int k0 = 0; k0 < K; k0 += 64) {
#pragma unroll
    for (int i = 0; i < 4; ++i) {
      int rbase = w * 32 + i * 8;
      int row = rbase + srow;
      int cb = scb ^ ((row & 7) << 4);        // inverse-swizzled source col (bytes)
      gl16((const char*)&X[(size_t)(m0 + row) * K + k0] + cb, &As[rbase * 64]);
      gl16((const char*)&Wt[(size_t)(n0 + row) * K + k0] + cb, &Bs[rbase * 64]);
    }
    __syncthreads();
    bf8 af[4][2], bfr[4][2];
#pragma unroll
    for (int mi = 0; mi < 4; ++mi)
#pragma unroll
      for (int kk = 0; kk < 2; ++kk)
        af[mi][kk] = *(const bf8*)&As[(wr * 64 + mi * 16 + lr) * 64 + ((kk * 32 + lk) ^ rsw)];
#pragma unroll
    for (int ni = 0; ni < 4; ++ni)
#pragma unroll
      for (int kk = 0; kk < 2; ++kk)
        bfr[ni][kk] = *(const bf8*)&Bs[(wc * 64 + ni * 16 + lr) * 64 + ((kk * 32 + lk) ^ rsw)];
#pragma unroll
    for (int kk = 0; kk < 2; ++kk)
#pragma unroll
      for (int mi = 0; mi < 4; ++mi)
#pragma unroll
        for (int ni = 0; ni < 4; ++ni)
          acc[mi][ni] = mfma16(af[mi][kk], bfr[ni][kk], acc[mi][ni]);
    __syncthreads();
  }
  const int lrg = (l >> 4) * 4;

  // bias (pre-LN, matching reference: LN(x@W^T + b))
  float bv[4];
#pragma unroll
  for (int ni = 0; ni < 4; ++ni) bv[ni] = bias[n0 + wc * 64 + ni * 16 + lr];
#pragma unroll
  for (int mi = 0; mi < 4; ++mi)
#pragma unroll
    for (int ni = 0; ni < 4; ++ni)
#pragma unroll
      for (int r = 0; r < 4; ++r) acc[mi][ni][r] += bv[ni];

  if constexpr (MODE == 2 || MODE == 3) {
    // per-row partial sums over this wave's 64 cols -> LDS -> combine
#pragma unroll
    for (int mi = 0; mi < 4; ++mi) {
#pragma unroll
      for (int r = 0; r < 4; ++r) {
        float ps = 0.f, pq = 0.f;
#pragma unroll
        for (int ni = 0; ni < 4; ++ni) {
          float v = acc[mi][ni][r];
          ps += v; pq += v * v;
        }
#pragma unroll
        for (int m = 1; m < 16; m <<= 1) {
          ps += __shfl_xor(ps, m);
          pq += __shfl_xor(pq, m);
        }
        if (lr == 0) {
          int rl = wr * 64 + mi * 16 + lrg + r;
          Sm[wc][rl] = ps; Sq[wc][rl] = pq;
        }
      }
    }
    __syncthreads();
    float gv[4], bbv[4];
#pragma unroll
    for (int ni = 0; ni < 4; ++ni) {
      int c = wc * 64 + ni * 16 + lr;          // col within head (n-tile aligned)
      gv[ni] = lng[c]; bbv[ni] = lnb[c];
    }
#pragma unroll
    for (int mi = 0; mi < 4; ++mi)
#pragma unroll
      for (int r = 0; r < 4; ++r) {
        int rl = wr * 64 + mi * 16 + lrg + r;
        float mean = (Sm[0][rl] + Sm[1][rl]) * (1.f / 128.f);
        float var  = (Sq[0][rl] + Sq[1][rl]) * (1.f / 128.f) - mean * mean;
        float rs = rsqrtf(var + LN_EPS);
#pragma unroll
        for (int ni = 0; ni < 4; ++ni) {
          float o = (acc[mi][ni][r] - mean) * rs * gv[ni] + bbv[ni];
          if (MODE == 3) o *= ATTN_SCALE;
          acc[mi][ni][r] = o;
        }
      }
  }

  if constexpr (MODE == 4) {
    // fused V-transpose: stage 128x128 bf16 tile in LDS (swizzled cols),
    // then write Y[bh][hd][kv] coalesced along kv.
    u16* T = &Sh[0][0];                        // 128*128 u16 = 32 KB
#pragma unroll
    for (int mi = 0; mi < 4; ++mi)
#pragma unroll
      for (int ni = 0; ni < 4; ++ni)
#pragma unroll
        for (int r = 0; r < 4; ++r) {
          int mrow = wr * 64 + mi * 16 + lrg + r;
          int ncol = wc * 64 + ni * 16 + lr;
          T[mrow * 128 + (ncol ^ ((mrow & 7) << 3))] = f2bf(acc[mi][ni][r]);
        }
    __syncthreads();
    int hd = tid >> 1, half = tid & 1;
    int bq = m0 >> 12;                          // m = b*LKV + kv, LKV=4096
    int kvb = (m0 & (LKV - 1)) + half * 64;
    int hh = n0 >> 7;                           // n-tile == head
    u16* vout = (u16*)Y + ((size_t)(bq * NH + hh) * HDm + hd) * LKV + kvb;
#pragma unroll
    for (int j8 = 0; j8 < 8; ++j8) {
      u16 tmp[8] __attribute__((aligned(16)));
#pragma unroll
      for (int j = 0; j < 8; ++j) {
        int kv = half * 64 + j8 * 8 + j;
        tmp[j] = T[kv * 128 + (hd ^ ((kv & 7) << 3))];
      }
      *(int4*)&vout[j8 * 8] = *(const int4*)tmp;
    }
    return;
  }

#pragma unroll
  for (int ni = 0; ni < 4; ++ni) {
    int n = n0 + wc * 64 + ni * 16 + lr;
#pragma unroll
    for (int mi = 0; mi < 4; ++mi) {
      int mb = m0 + wr * 64 + mi * 16 + lrg;
#pragma unroll
      for (int r = 0; r < 4; ++r) {
        float v = acc[mi][ni][r];
        if constexpr (MODE == 1)
          __builtin_nontemporal_store(v, &((float*)Y)[(size_t)(mb + r) * N + n]);
        else
          ((u16*)Y)[(size_t)(mb + r) * N + n] = f2bf(v);
      }
    }
  }
}

// ---------------- fused attention (swapped-operand QK, T12-style) ----------
// 512 threads / 8 waves, q-tile 128. Pass A: kv-tile 128 (Ks+Vs unioned as two
// 32KB dbuf regions), lane-local row sums. Pass B: kv-tile 64, dbuf, Ps
// ELIMINATED: P stays in registers (lane lr owns q-row lr), pf assembled via
// shfl; Wout written as f32x4 nontemporal. One barrier + counted vmcnt/iter.
__global__ __launch_bounds__(512, 4) void k_attn(const u16* __restrict__ Qp,
                                                 const u16* __restrict__ Kp,
                                                 const u16* __restrict__ Vt,
                                                 float* __restrict__ Wout,
                                                 u16* __restrict__ AO) {
  const int g = blockIdx.x;                 // 512 blocks, 8 XCDs, 64 each
  const int work = (g & 7) * 64 + (g >> 3);
  const int bh = work >> 4;
  const int b = bh >> 4, h = bh & 15;
  const int q0 = (work & 15) * 128;
  const int tid = threadIdx.x, w = tid >> 6, l = tid & 63;
  const int lr = l & 15, lk = (l >> 4) * 8;
  const int gq = l >> 4;                    // lane group 0..3 (kv sub-quad)
  const int rsw = (l & 7) << 3;             // read swizzle, u16 units
  __shared__ __align__(16) u16 Ks[2][64 * 128];
  __shared__ __align__(16) u16 Vs[2][128 * 64];

  // hoist Q fragments (B-frag for swapped mfma: col = lr, 8 k-els at kc*32+lk)
  bf8 qf[4];
  {
    const u16* qb = &Qp[((size_t)b * LQ + q0 + w * 16 + lr) * DD + h * HDm];
#pragma unroll
    for (int kc = 0; kc < 4; ++kc) qf[kc] = *(const bf8*)(qb + kc * 32 + lk);
  }
  const u16* Kb = Kp + (size_t)b * LKV * DD + h * HDm;   // row stride DD
  const u16* Vb = Vt + (size_t)bh * HDm * LKV;           // row (hd) stride LKV

  // ---- staging helpers
  auto stageK128 = [&](u16* buf, int kv0) {   // 128 rows x 256 B into 32KB region
#pragma unroll
    for (int i = 0; i < 4; ++i) {
      int rbase = i * 32 + w * 4;
      int row = rbase + (l >> 4);
      int cb = ((l & 15) * 16) ^ ((row & 7) << 4);
      gl16((const char*)(Kb + (size_t)(kv0 + row) * DD) + cb, &buf[rbase * 128]);
    }
  };
  auto stageK = [&](int buf, int kv0) {       // 64 rows x 256 B
#pragma unroll
    for (int i = 0; i < 2; ++i) {
      int rbase = i * 32 + w * 4;
      int row = rbase + (l >> 4);
      int cb = ((l & 15) * 16) ^ ((row & 7) << 4);
      gl16((const char*)(Kb + (size_t)(kv0 + row) * DD) + cb, &Ks[buf][rbase * 128]);
    }
  };
  auto stageV = [&](int buf, int kv0) {       // 128 rows x 128 B
#pragma unroll
    for (int i = 0; i < 2; ++i) {
      int rbase = i * 64 + w * 8;
      int row = rbase + (l >> 3);
      int cb = ((l & 7) * 16) ^ ((row & 7) << 4);
      gl16((const char*)(Vb + (size_t)row * LKV + kv0) + cb, &Vs[buf][rbase * 64]);
    }
  };

  // ================= pass A: lane-local row sums, kv-tile 128 ==============
  u16* bufA0 = &Ks[0][0];                    // 32KB region = 128 rows x 128 u16
  u16* bufA1 = &Vs[0][0];
  float lsum = 0.f;
  stageK128(bufA0, 0);
  asm volatile("s_waitcnt vmcnt(0)" ::: "memory");
  barrier_hard();
  for (int t = 0; t < 32; ++t) {
    const u16* kb = (t & 1) ? bufA1 : bufA0;
    if (t < 31) stageK128((t & 1) ? bufA0 : bufA1, (t + 1) * 128);
    f32x4 s8[8];
    __builtin_amdgcn_s_setprio(1);
#pragma unroll
    for (int ni = 0; ni < 8; ++ni) {
      s8[ni] = f32x4{0.f, 0.f, 0.f, 0.f};
#pragma unroll
      for (int kc = 0; kc < 4; ++kc) {
        bf8 kf = *(const bf8*)&kb[(ni * 16 + lr) * 128 + ((kc * 32 + lk) ^ rsw)];
        s8[ni] = mfma16(kf, qf[kc], s8[ni]);
      }
    }
    __builtin_amdgcn_s_setprio(0);
#pragma unroll
    for (int ni = 0; ni < 8; ++ni)
#pragma unroll
      for (int r = 0; r < 4; ++r)
        lsum += exp2f(fmaf(s8[ni][r], LOG2E, -SHIFT2));
    asm volatile("s_waitcnt vmcnt(0)" ::: "memory");  // next tile staged
    barrier_hard();
  }
  // lane lr holds partials of q-row lr; combine the 4 lane-groups
  lsum += __shfl_xor(lsum, 16);
  lsum += __shfl_xor(lsum, 32);
  const float cr = -(SHIFT2 + __log2f(lsum));   // exp2(s*log2e + cr) = p/sum

  // ================= pass B: weights + PV, kv-tile 64 =======================
  f32x4 oacc[8] = {};
  float* wq = Wout + ((size_t)bh * LQ + q0 + w * 16 + lr) * LKV;
  const int srcA = lr + ((gq & 1) << 5);
  const int srcB = srcA + 16;
  const bool hi = (gq >> 1) != 0;

  stageK(0, 0); stageV(0, 0);
  asm volatile("s_waitcnt vmcnt(0)" ::: "memory");
  barrier_hard();
  for (int t = 0; t < 64; ++t) {
    const int cur = t & 1;
    const int kv0 = t * 64;
    if (t < 63) { stageK(cur ^ 1, kv0 + 64); stageV(cur ^ 1, kv0 + 64); }
    // QK swapped: s[ni] rows = kv (ni*16 + 4*gq + r), col = q-row lr
    f32x4 s[4];
    __builtin_amdgcn_s_setprio(1);
#pragma unroll
    for (int ni = 0; ni < 4; ++ni) {
      s[ni] = f32x4{0.f, 0.f, 0.f, 0.f};
#pragma unroll
      for (int kc = 0; kc < 4; ++kc) {
        bf8 kf = *(const bf8*)&Ks[cur][(ni * 16 + lr) * 128 + ((kc * 32 + lk) ^ rsw)];
        s[ni] = mfma16(kf, qf[kc], s[ni]);
      }
    }
    __builtin_amdgcn_s_setprio(0);
    // normalized p: 4 contiguous kv per lane -> f32x4 nontemporal stores
    unsigned pk2[4][2];
#pragma unroll
    for (int ni = 0; ni < 4; ++ni) {
      float p0 = exp2f(fmaf(s[ni][0], LOG2E, cr));
      float p1 = exp2f(fmaf(s[ni][1], LOG2E, cr));
      float p2 = exp2f(fmaf(s[ni][2], LOG2E, cr));
      float p3 = exp2f(fmaf(s[ni][3], LOG2E, cr));
      f32x4 pv4 = {p0, p1, p2, p3};
      __builtin_nontemporal_store(pv4, (f32x4*)(wq + kv0 + ni * 16 + 4 * gq));
      pk2[ni][0] = (unsigned)f2bf(p0) | ((unsigned)f2bf(p1) << 16);
      pk2[ni][1] = (unsigned)f2bf(p2) | ((unsigned)f2bf(p3) << 16);
    }
    // assemble pf (A-frag of PV: q-row lr, 8 kv at kk*32+8*gq) via shfl + PV
#pragma unroll
    for (int kk = 0; kk < 2; ++kk) {
      unsigned xa0 = __shfl(pk2[2 * kk][0], srcA), xa1 = __shfl(pk2[2 * kk][1], srcA);
      unsigned ya0 = __shfl(pk2[2 * kk + 1][0], srcA), ya1 = __shfl(pk2[2 * kk + 1][1], srcA);
      unsigned xb0 = __shfl(pk2[2 * kk][0], srcB), xb1 = __shfl(pk2[2 * kk][1], srcB);
      unsigned yb0 = __shfl(pk2[2 * kk + 1][0], srcB), yb1 = __shfl(pk2[2 * kk + 1][1], srcB);
      u32x4 pf32 = { hi ? ya0 : xa0, hi ? ya1 : xa1, hi ? yb0 : xb0, hi ? yb1 : xb1 };
      bf8 pf = __builtin_bit_cast(bf8, pf32);
      __builtin_amdgcn_s_setprio(1);
#pragma unroll
      for (int c = 0; c < 8; ++c) {
        bf8 vf = *(const bf8*)&Vs[cur][(c * 16 + lr) * 64 + ((kk * 32 + lk) ^ rsw)];
        oacc[c] = mfma16(pf, vf, oacc[c]);
      }
      __builtin_amdgcn_s_setprio(0);
    }
    // drain the 4 prefetch loads; leave the 4 newest (stores) in flight
    asm volatile("s_waitcnt vmcnt(4)" ::: "memory");
    barrier_hard();
  }

  // epilogue: AO [B, Lq, D] bf16 (oacc rows q = 4*gq + r, cols hd = c*16+lr)
#pragma unroll
  for (int c = 0; c < 8; ++c)
#pragma unroll
    for (int r = 0; r < 4; ++r)
      AO[((size_t)b * LQ + q0 + w * 16 + 4 * gq + r) * DD + h * HDm + c * 16 + lr] =
          f2bf(oacc[c][r]);
}

// ---------------------------------------------------------------------------
extern "C" void kernel_launch(void* const* d_in, const int* in_sizes, int n_in,
                              void* d_out, int out_size, void* d_ws, size_t ws_size,
                              hipStream_t stream) {
  const float* hs   = (const float*)d_in[0];
  const float* cas  = (const float*)d_in[1];
  const float* q_w  = (const float*)d_in[2];
  const float* q_b  = (const float*)d_in[3];
  const float* k_w  = (const float*)d_in[4];
  const float* k_b  = (const float*)d_in[5];
  const float* v_w  = (const float*)d_in[6];
  const float* v_b  = (const float*)d_in[7];
  const float* o_w  = (const float*)d_in[8];
  const float* o_b  = (const float*)d_in[9];
  const float* qn_g = (const float*)d_in[10];
  const float* qn_b = (const float*)d_in[11];
  const float* kn_g = (const float*)d_in[12];
  const float* kn_b = (const float*)d_in[13];

  float* out_attn = (float*)d_out;
  float* out_w    = out_attn + (size_t)BB * LQ * DD;

  constexpr size_t SZ_Q  = (size_t)BB * LQ * DD * 2;
  constexpr size_t SZ_KV = (size_t)BB * LKV * DD * 2;
  constexpr size_t SZ_W  = (size_t)DD * DD * 2;
  char* p = (char*)d_ws;
  u16* hsb  = (u16*)p;              p += SZ_Q;
  u16* casb = (u16*)p;              p += SZ_KV;
  u16* qwb  = (u16*)p;              p += SZ_W;
  u16* kwb  = (u16*)p;              p += SZ_W;
  u16* vwb  = (u16*)p;              p += SZ_W;
  u16* owb  = (u16*)p;              p += SZ_W;
  u16* Qp   = (u16*)p;              p += SZ_Q;
  u16* Kp   = (u16*)p;              p += SZ_KV;
  u16* Vtp  = (u16*)p;              p += SZ_KV;
  u16* AO   = (u16*)p;              p += SZ_Q;

  auto cvt = [&](const float* src, u16* dst, size_t n) {
    int n4 = (int)(n / 4);
    k_cvt<<<dim3((n4 + 255) / 256), dim3(256), 0, stream>>>(
        (const float4*)src, (ushort4*)dst, n4);
  };
  cvt(hs,  hsb,  (size_t)BB * LQ * DD);
  cvt(cas, casb, (size_t)BB * LKV * DD);
  cvt(q_w, qwb, (size_t)DD * DD);
  cvt(k_w, kwb, (size_t)DD * DD);
  cvt(v_w, vwb, (size_t)DD * DD);
  cvt(o_w, owb, (size_t)DD * DD);

  // projections; LN fused for Q (with ATTN_SCALE) and K; V writes transposed
  k_gemm_nt<3><<<dim3(BB * LQ / 128, DD / 128), dim3(256), 0, stream>>>(
      hsb, qwb, q_b, qn_g, qn_b, Qp, BB * LQ, DD, DD);
  k_gemm_nt<2><<<dim3(BB * LKV / 128, DD / 128), dim3(256), 0, stream>>>(
      casb, kwb, k_b, kn_g, kn_b, Kp, BB * LKV, DD, DD);
  k_gemm_nt<4><<<dim3(BB * LKV / 128, DD / 128), dim3(256), 0, stream>>>(
      casb, vwb, v_b, nullptr, nullptr, Vtp, BB * LKV, DD, DD);

  k_attn<<<dim3(LQ / 128 * BB * NH), dim3(512), 0, stream>>>(Qp, Kp, Vtp, out_w, AO);

  k_gemm_nt<1><<<dim3(BB * LQ / 128, DD / 128), dim3(256), 0, stream>>>(
      AO, owb, o_b, nullptr, nullptr, out_attn, BB * LQ, DD, DD);
}